// Round 8
// baseline (349.286 us; speedup 1.0000x reference)
//
#include <hip/hip_runtime.h>
#include <stdint.h>

// Problem constants: B=8, T=1024, E=1024, H=16, D=64
#define BB 8
#define TT 1024
#define EE 1024
#define HH 16
#define DD 64

// log2(e)/8: folded into Q projection so attention uses exp2 directly
#define L2E8 0.18033688011112042f

typedef __attribute__((ext_vector_type(8))) __bf16 bf16x8;
typedef __attribute__((ext_vector_type(4))) float f32x4;
typedef __attribute__((ext_vector_type(4))) unsigned short ushort4v;
typedef __attribute__((ext_vector_type(4))) unsigned int uint4v;

__device__ __forceinline__ unsigned short f2bf(float f) {
  unsigned int u = __float_as_uint(f);
  u += 0x7fffu + ((u >> 16) & 1u);   // RNE (finite data)
  return (unsigned short)(u >> 16);
}

// pack two f32 -> bf16x2 with round-half-up: 2 adds + 1 v_perm (vs ~8 ops RNE)
__device__ __forceinline__ unsigned int pk2t(float a, float b) {
  return __builtin_amdgcn_perm(__float_as_uint(b) + 0x8000u,
                               __float_as_uint(a) + 0x8000u, 0x07060302u);
}

__device__ __forceinline__ f32x4 mfma_16x16x32(bf16x8 a, bf16x8 b, f32x4 c) {
  return __builtin_amdgcn_mfma_f32_16x16x32_bf16(a, b, c, 0, 0, 0);
}

// async global->LDS, 16B per lane; LDS dest must be wave-uniform base + lane*16
__device__ __forceinline__ void async_ld16(const unsigned short* g, unsigned short* l) {
  __builtin_amdgcn_global_load_lds(
      (const __attribute__((address_space(1))) void*)g,
      (__attribute__((address_space(3))) void*)l, 16, 0, 0);
}

// -------------------- cast fp32 -> bf16 for Wo only --------------------
// Round-8: the big cast_all (168MB HBM round trip, ~25us) is FUSED into fused_proj
// (reads fp32 directly, converts in-register). Only Wo still needs a bf16 copy
// for gemm_out: 4MB read / 2MB write, ~1.5us.
__global__ __launch_bounds__(256) void cast_wo(
    const float* __restrict__ wo, unsigned short* __restrict__ dst) {
  size_t base = (size_t)blockIdx.x * 2048 + (size_t)threadIdx.x * 8;
  float4 a = *(const float4*)(wo + base);
  float4 b = *(const float4*)(wo + base + 4);
  ushort4v o0, o1;
  o0.x = f2bf(a.x); o0.y = f2bf(a.y); o0.z = f2bf(a.z); o0.w = f2bf(a.w);
  o1.x = f2bf(b.x); o1.y = f2bf(b.y); o1.z = f2bf(b.z); o1.w = f2bf(b.w);
  *(ushort4v*)(dst + base) = o0;
  *(ushort4v*)(dst + base + 4) = o1;
}

// -------------------- fused Q/K/V projection (fp32 in, fused cast) --------------------
// Compute structure = r5 (best measured: 128x128, BK=64, counted schedule, T2 swizzle,
// XCD-local n-major maps; 2 blocks/CU). r7's 8-phase 256^2 regressed (44us/block at
// 1 blk/CU + 1.5x grid imbalance) and is reverted.
// NEW: staging reads the ORIGINAL fp32 tensors (cast_all eliminated): per tile each
// thread issues 16 global_load_dwordx4 (fp32), converts via pk2t, ds_write_b128 into
// the same swizzled bf16 LDS layout as before (read path unchanged).
// T14 schedule per iter: compute(buf[cur]) -> B1 -> vmcnt(0) [loads from LAST iter
// landed: full compute phase of slack] -> write buf[cur^1] -> issue L(t+2) ->
// lgkmcnt(0) -> B2. Every buffer has >=2 barriers between last-read and overwrite.
// 1536 blocks, flat id: [0,512) Q, [512,1024) K, [1024,1536) V^T.
__global__ __launch_bounds__(256, 2) void fused_proj(
    const float* __restrict__ xq, const float* __restrict__ xk,
    const float* __restrict__ xv, const float* __restrict__ wq,
    const float* __restrict__ wk, const float* __restrict__ wv,
    const float* __restrict__ bq, const float* __restrict__ bk, const float* __restrict__ bv,
    unsigned short* __restrict__ Qb, unsigned short* __restrict__ Kb,
    unsigned short* __restrict__ Vtb) {
  const int id = blockIdx.x;
  const int tid = threadIdx.x;
  const int wave = tid >> 6, lane = tid & 63;
  const int quad = lane >> 4, l16 = lane & 15;
  const int wr = wave >> 1, wc = wave & 1;

  const float *A, *W;
  const float* bias;
  int mode, m0, n0;
  size_t zoff = 0;
  if (id < 512) {
    mode = 0; A = xq; W = wq; bias = bq;
    m0 = (id & 63) * 128; n0 = (id >> 6) * 128;          // n-major (XCD-local A)
  } else if (id < 1024) {
    int t = id - 512;
    mode = 1; A = xk; W = wk; bias = bk;
    m0 = (t & 63) * 128; n0 = (t >> 6) * 128;            // n-major
  } else {
    int t = id - 1024;
    int z = t >> 6;
    mode = 2; A = wv; W = xv + (size_t)z * 1048576; bias = bv;
    m0 = ((t >> 3) & 7) * 128; n0 = (t & 7) * 128;       // already XCD-local
    zoff = (size_t)z * 1048576;
  }

  __shared__ __align__(16) unsigned short As[2][128 * 64];
  __shared__ __align__(16) unsigned short Bs[2][128 * 64];

  const float* Wb = W + (size_t)n0 * 1024;

  f32x4 acc[4][4];
#pragma unroll
  for (int i = 0; i < 4; ++i)
#pragma unroll
    for (int j = 0; j < 4; ++j) acc[i][j] = (f32x4){0.f, 0.f, 0.f, 0.f};

  const int row_s = tid >> 3, c_s = tid & 7;
  const int swl = l16 & 7;           // read-side swizzle key (row&7 == l16&7)

  // in-flight fp32 for one tile: 8 float4 A + 8 float4 B = 64 VGPR
  float4 ra[8], rb[8];

  // issue global loads for tile kt (pre-swizzled source chunk, same map as before)
  auto issue = [&](int kt) {
    const float* Akt = A + (size_t)m0 * 1024 + kt * 64;
    const float* Wkt = Wb + kt * 64;
#pragma unroll
    for (int i = 0; i < 4; ++i) {
      int row = row_s + i * 32;
      int gc = c_s ^ (row & 7);
      const float* pa = Akt + (size_t)row * 1024 + gc * 8;
      const float* pb = Wkt + (size_t)row * 1024 + gc * 8;
      ra[2 * i]     = *(const float4*)pa;
      ra[2 * i + 1] = *(const float4*)(pa + 4);
      rb[2 * i]     = *(const float4*)pb;
      rb[2 * i + 1] = *(const float4*)(pb + 4);
    }
  };
  // convert + write the held tile into LDS slot sel (layout identical to old staging)
  auto writeLds = [&](int sel) {
#pragma unroll
    for (int i = 0; i < 4; ++i) {
      int g = i * 256 + tid;
      uint4v ua, ub;
      ua.x = pk2t(ra[2 * i].x, ra[2 * i].y);
      ua.y = pk2t(ra[2 * i].z, ra[2 * i].w);
      ua.z = pk2t(ra[2 * i + 1].x, ra[2 * i + 1].y);
      ua.w = pk2t(ra[2 * i + 1].z, ra[2 * i + 1].w);
      ub.x = pk2t(rb[2 * i].x, rb[2 * i].y);
      ub.y = pk2t(rb[2 * i].z, rb[2 * i].w);
      ub.z = pk2t(rb[2 * i + 1].x, rb[2 * i + 1].y);
      ub.w = pk2t(rb[2 * i + 1].z, rb[2 * i + 1].w);
      *(uint4v*)(&As[sel][g * 8]) = ua;
      *(uint4v*)(&Bs[sel][g * 8]) = ub;
    }
  };

  issue(0);
  asm volatile("s_waitcnt vmcnt(0)" ::: "memory");
  writeLds(0);
  issue(1);                                            // fly during write drain
  asm volatile("s_waitcnt lgkmcnt(0)" ::: "memory");
  __builtin_amdgcn_s_barrier();                        // buf0 ready

  for (int kt = 0; kt < 16; ++kt) {
    const int cur = kt & 1;
    // invariant: buf[cur]=tile kt ready; regs hold fp32 of tile kt+1 (in flight)
#pragma unroll
    for (int ks = 0; ks < 2; ++ks) {
      bf16x8 af[4], bfv[4];
      const int sc = (ks * 4 + quad) ^ swl;            // swizzled LDS chunk slot
#pragma unroll
      for (int i = 0; i < 4; ++i)
        af[i] = *(const bf16x8*)(&As[cur][((wr * 64 + i * 16 + l16) * 8 + sc) * 8]);
#pragma unroll
      for (int j = 0; j < 4; ++j)
        bfv[j] = *(const bf16x8*)(&Bs[cur][((wc * 64 + j * 16 + l16) * 8 + sc) * 8]);
      __builtin_amdgcn_s_setprio(1);
#pragma unroll
      for (int i = 0; i < 4; ++i)
#pragma unroll
        for (int j = 0; j < 4; ++j) acc[i][j] = mfma_16x16x32(af[i], bfv[j], acc[i][j]);
      __builtin_amdgcn_s_setprio(0);
    }
    __builtin_amdgcn_s_barrier();                      // B1: done reading buf[cur]
    if (kt < 15) {
      asm volatile("s_waitcnt vmcnt(0)" ::: "memory"); // tile kt+1 fp32 landed
      writeLds(cur ^ 1);                               // buf[cur^1]: free since B1(kt-1)
      if (kt < 14) issue(kt + 2);                      // in flight across next compute
      asm volatile("s_waitcnt lgkmcnt(0)" ::: "memory");
    }
    __builtin_amdgcn_s_barrier();                      // B2: buf[cur^1] ready
  }

  if (mode == 2) {
    const int nxor = ((((l16 >> 2) + 1) & 2) ? 12 : 0);
#pragma unroll
    for (int i = 0; i < 4; ++i)
#pragma unroll
      for (int r = 0; r < 4; ++r) {
        int m = m0 + wr * 64 + i * 16 + quad * 4 + r;
        float bm = bias[m];
#pragma unroll
        for (int j = 0; j < 4; ++j) {
          int n = (n0 + wc * 64 + j * 16 + l16) ^ nxor;
          Vtb[zoff + (size_t)m * 1024 + n] = f2bf(acc[i][j][r] + bm);
        }
      }
  } else {
    unsigned short* Out = (mode == 0) ? Qb : Kb;
    const float scale = (mode == 0) ? L2E8 : 1.0f;
#pragma unroll
    for (int j = 0; j < 4; ++j) {
      int n = n0 + wc * 64 + j * 16 + l16;
      float bn = bias[n];
      int h = n >> 6, d = n & 63;
#pragma unroll
      for (int i = 0; i < 4; ++i)
#pragma unroll
        for (int r = 0; r < 4; ++r) {
          int m = m0 + wr * 64 + i * 16 + quad * 4 + r;
          int b = m >> 10, t = m & 1023;
          float v = (acc[i][j][r] + bn) * scale;
          Out[((size_t)((b << 4) + h) * 1024 + t) * 64 + d] = f2bf(v);
        }
    }
  }
}

// -------------------- final GEMM: out = O @ Wo^T + bo (fp32 out) --------------------
// BM=64, BN=128. A is (B,H,T,D): m=b*1024+t, k=h*64+d.
// Counted-vmcnt schedule; grid dim3(128,8) keeps A-panel siblings XCD-local.
__global__ __launch_bounds__(256, 3) void gemm_out(
    const unsigned short* __restrict__ A, const unsigned short* __restrict__ Wm,
    const float* __restrict__ bias, float* __restrict__ Cout) {
  const int tid = threadIdx.x;
  const int wave = tid >> 6, lane = tid & 63;
  const int quad = lane >> 4, l16 = lane & 15;
  const int wr = wave >> 1, wc = wave & 1;   // wave tile: 32m x 64n
  const int m0 = blockIdx.x * 64;
  const int n0 = blockIdx.y * 128;

  __shared__ __align__(16) unsigned short As[2][64 * 64];
  __shared__ __align__(16) unsigned short Bs[2][128 * 64];

  const unsigned short* Wb = Wm + (size_t)n0 * 1024;

  f32x4 acc[2][4];
#pragma unroll
  for (int i = 0; i < 2; ++i)
#pragma unroll
    for (int j = 0; j < 4; ++j) acc[i][j] = (f32x4){0.f, 0.f, 0.f, 0.f};

  const int row_s = tid >> 3, c_s = tid & 7;
  const int swl = l16 & 7;

  // 6 async_ld16 per wave per stage (A: 2, B: 4) -> vmcnt += 6
  auto stage = [&](int sel, int kt) {
    const unsigned short* Akt =
        A + (size_t)(m0 >> 10) * 1048576 + (size_t)kt * 65536 + (size_t)(m0 & 1023) * 64;
    const unsigned short* Wkt = Wb + kt * 64;
#pragma unroll
    for (int i = 0; i < 2; ++i) {
      int row = row_s + i * 32;
      int gc = c_s ^ (row & 7);
      async_ld16(Akt + (size_t)row * 64 + gc * 8, &As[sel][(i * 256 + tid) * 8]);
    }
#pragma unroll
    for (int i = 0; i < 4; ++i) {
      int row = row_s + i * 32;
      int gc = c_s ^ (row & 7);
      async_ld16(Wkt + (size_t)row * 1024 + gc * 8, &Bs[sel][(i * 256 + tid) * 8]);
    }
  };

  stage(0, 0);                                   //  6 in flight
  stage(1, 1);                                   // 12 in flight
  asm volatile("s_waitcnt vmcnt(6)" ::: "memory");
  __builtin_amdgcn_s_barrier();

  for (int kt = 0; kt < 16; ++kt) {
    const int cur = kt & 1;
#pragma unroll
    for (int ks = 0; ks < 2; ++ks) {
      bf16x8 af[2], bfv[4];
      const int sc = (ks * 4 + quad) ^ swl;
#pragma unroll
      for (int i = 0; i < 2; ++i)
        af[i] = *(const bf16x8*)(&As[cur][((wr * 32 + i * 16 + l16) * 8 + sc) * 8]);
#pragma unroll
      for (int j = 0; j < 4; ++j)
        bfv[j] = *(const bf16x8*)(&Bs[cur][((wc * 64 + j * 16 + l16) * 8 + sc) * 8]);
      __builtin_amdgcn_s_setprio(1);
#pragma unroll
      for (int i = 0; i < 2; ++i)
#pragma unroll
        for (int j = 0; j < 4; ++j) acc[i][j] = mfma_16x16x32(af[i], bfv[j], acc[i][j]);
      __builtin_amdgcn_s_setprio(0);
    }
    __builtin_amdgcn_s_barrier();                // B1: done reading buf[cur]
    int ktc = kt + 2 > 15 ? 15 : kt + 2;
    stage(cur, ktc);
    asm volatile("s_waitcnt vmcnt(6)" ::: "memory");
    __builtin_amdgcn_s_barrier();                // B2: buf[cur^1] ready
  }

#pragma unroll
  for (int j = 0; j < 4; ++j) {
    int n = n0 + wc * 64 + j * 16 + l16;
    float bn = bias[n];
#pragma unroll
    for (int i = 0; i < 2; ++i)
#pragma unroll
      for (int r = 0; r < 4; ++r) {
        int m = m0 + wr * 32 + i * 16 + quad * 4 + r;
        Cout[(size_t)m * 1024 + n] = acc[i][j][r] + bn;
      }
  }
}

// -------------------- attention: S^T form + LDS-staged K/V tiles --------------------
// r5 version (16 q-rows/wave, grid (128,16)) -- the r6 32-q variant measured ~6us
// worse net; reverted. setprio around MFMA clusters (T5).
__global__ __launch_bounds__(256) void attn(
    const unsigned short* __restrict__ Q,   // (B,H,T,D), pre-scaled by log2e/8
    const unsigned short* __restrict__ K,   // (B,H,T,D)
    const unsigned short* __restrict__ Vt,  // (B,H,D,T), T pi-permuted per 32-block
    unsigned short* __restrict__ O) {       // (B,H,T,D)
  const int bh = blockIdx.x;
  const int tid = threadIdx.x;
  const int wave = tid >> 6, lane = tid & 63;
  const int quad = lane >> 4, l16 = lane & 15;
  const int q0 = blockIdx.y * 64 + wave * 16;
  const size_t bhTD = (size_t)bh * (TT * DD);
  const unsigned short* Qb = Q + bhTD;
  const unsigned short* Kb = K + bhTD;
  const unsigned short* Vb = Vt + bhTD;

  __shared__ __align__(16) unsigned short Ks[64 * 64];
  __shared__ __align__(16) unsigned short Vs[64 * 64];

  bf16x8 q_lo = *(const bf16x8*)(Qb + (size_t)(q0 + l16) * 64 + quad * 8);
  bf16x8 q_hi = *(const bf16x8*)(Qb + (size_t)(q0 + l16) * 64 + 32 + quad * 8);

  uint4v ou; ou.x = ou.y = ou.z = ou.w = 0x3F803F80u;   // bf16 1.0 x8
  const bf16x8 ones = __builtin_bit_cast(bf16x8, ou);

  f32x4 o_acc[4];
#pragma unroll
  for (int dd = 0; dd < 4; ++dd) o_acc[dd] = (f32x4){0.f, 0.f, 0.f, 0.f};
  f32x4 acc5 = (f32x4){0.f, 0.f, 0.f, 0.f};             // per-row sum of P-hat
  const bool lo_half = (quad < 2);

  const int srow = tid >> 3;
  const int schunk = tid & 7;

  for (int it = 0; it < 16; ++it) {
    const int kv0 = it * 64;
#pragma unroll
    for (int i = 0; i < 2; ++i) {
      int row = srow + i * 32;
      int gc = schunk ^ (row & 7);
      async_ld16(Kb + (size_t)(kv0 + row) * 64 + gc * 8, Ks + (row * 8 + schunk) * 8);
      async_ld16(Vb + (size_t)row * 1024 + kv0 + gc * 8, Vs + (row * 8 + schunk) * 8);
    }
    __syncthreads();

    // ---- phase 1: all S-MFMAs for both 32-kv halves ----
    f32x4 f[4];
#pragma unroll
    for (int c = 0; c < 2; ++c) {
      const int r0 = c * 32 + l16;
      const int r1 = r0 + 16;
      const int sw = r0 & 7;
      bf16x8 k00 = *(const bf16x8*)(Ks + (r0 * 8 + (quad ^ sw)) * 8);
      bf16x8 k01 = *(const bf16x8*)(Ks + (r0 * 8 + ((quad + 4) ^ sw)) * 8);
      bf16x8 k10 = *(const bf16x8*)(Ks + (r1 * 8 + (quad ^ sw)) * 8);
      bf16x8 k11 = *(const bf16x8*)(Ks + (r1 * 8 + ((quad + 4) ^ sw)) * 8);
      f32x4 a = (f32x4){0.f, 0.f, 0.f, 0.f};
      f32x4 b = (f32x4){0.f, 0.f, 0.f, 0.f};
      __builtin_amdgcn_s_setprio(1);
      a = mfma_16x16x32(k00, q_lo, a);
      a = mfma_16x16x32(k01, q_hi, a);
      b = mfma_16x16x32(k10, q_lo, b);
      b = mfma_16x16x32(k11, q_hi, b);
      __builtin_amdgcn_s_setprio(0);
      f[2 * c] = a; f[2 * c + 1] = b;
    }

    // ---- phase 2: exp2, pack, A-frag build, denominator + PV MFMAs ----
#pragma unroll
    for (int c = 0; c < 2; ++c) {
      f32x4 f0 = f[2 * c], f1 = f[2 * c + 1];
      float p0 = __builtin_amdgcn_exp2f(f0[0]), p1 = __builtin_amdgcn_exp2f(f0[1]);
      float p2 = __builtin_amdgcn_exp2f(f0[2]), p3 = __builtin_amdgcn_exp2f(f0[3]);
      float p4 = __builtin_amdgcn_exp2f(f1[0]), p5 = __builtin_amdgcn_exp2f(f1[1]);
      float p6 = __builtin_amdgcn_exp2f(f1[2]), p7 = __builtin_amdgcn_exp2f(f1[3]);
      unsigned int u01 = pk2t(p0, p1), u23 = pk2t(p2, p3);
      unsigned int u45 = pk2t(p4, p5), u67 = pk2t(p6, p7);
      unsigned int pu01 = __shfl_xor(u01, 32), pu23 = __shfl_xor(u23, 32);
      unsigned int pu45 = __shfl_xor(u45, 32), pu67 = __shfl_xor(u67, 32);
      uint4v av;
      av.x = lo_half ? u01 : pu45;
      av.y = lo_half ? u23 : pu67;
      av.z = lo_half ? pu01 : u45;
      av.w = lo_half ? pu23 : u67;
      bf16x8 ap = __builtin_bit_cast(bf16x8, av);
      __builtin_amdgcn_s_setprio(1);
      acc5 = mfma_16x16x32(ap, ones, acc5);
#pragma unroll
      for (int dd = 0; dd < 4; ++dd) {
        int vr = dd * 16 + l16;
        bf16x8 bv = *(const bf16x8*)(Vs + (vr * 8 + ((c * 4 + quad) ^ (vr & 7))) * 8);
        o_acc[dd] = mfma_16x16x32(ap, bv, o_acc[dd]);
      }
      __builtin_amdgcn_s_setprio(0);
    }
    __syncthreads();
  }
#pragma unroll
  for (int r = 0; r < 4; ++r) {
    float invr = 1.f / acc5[r];    // acc5[r] = sum_k P[q=quad*4+r][k], same at every lane
    int trow = q0 + quad * 4 + r;
#pragma unroll
    for (int dd = 0; dd < 4; ++dd)
      O[bhTD + (size_t)trow * 64 + dd * 16 + l16] = f2bf(o_acc[dd][r] * invr);
  }
}

// -------------------- launch --------------------
extern "C" void kernel_launch(void* const* d_in, const int* in_sizes, int n_in,
                              void* d_out, int out_size, void* d_ws, size_t ws_size,
                              hipStream_t stream) {
  const float* xq = (const float*)d_in[0];
  const float* xk = (const float*)d_in[1];
  const float* xv = (const float*)d_in[2];
  const float* Wq = (const float*)d_in[3];
  const float* bq = (const float*)d_in[4];
  const float* Wk = (const float*)d_in[5];
  const float* bk = (const float*)d_in[6];
  const float* Wv = (const float*)d_in[7];
  const float* bv = (const float*)d_in[8];
  const float* Wo = (const float*)d_in[9];
  const float* bo = (const float*)d_in[10];

  unsigned short* ws = (unsigned short*)d_ws;
  unsigned short* wo_b = ws;                  // 1048576 (bf16 Wo)
  unsigned short* Qbuf = ws + 1048576;        // 8388608 each, (B,H,T,D)
  unsigned short* Kbuf = ws + 9437184;
  unsigned short* Vtb  = ws + 17825792;       // (B,H,D,T) pi-permuted
  unsigned short* Obuf = ws + 26214400;       // (B,H,T,D)

  cast_wo<<<512, 256, 0, stream>>>(Wo, wo_b);

  fused_proj<<<1536, 256, 0, stream>>>(xq, xk, xv, Wq, Wk, Wv,
                                       bq, bk, bv, Qbuf, Kbuf, Vtb);
  attn<<<dim3(128, 16), 256, 0, stream>>>(Qbuf, Kbuf, Vtb, Obuf);
  gemm_out<<<dim3(128, 8), 256, 0, stream>>>(Obuf, wo_b, bo, (float*)d_out);
}

// Round 9
// 302.255 us; speedup vs baseline: 1.1556x; 1.1556x over previous
//
#include <hip/hip_runtime.h>
#include <stdint.h>

// Problem constants: B=8, T=1024, E=1024, H=16, D=64
#define BB 8
#define TT 1024
#define EE 1024
#define HH 16
#define DD 64

// log2(e)/8: folded into Q projection so attention uses exp2 directly
#define L2E8 0.18033688011112042f

typedef __attribute__((ext_vector_type(8))) __bf16 bf16x8;
typedef __attribute__((ext_vector_type(4))) float f32x4;
typedef __attribute__((ext_vector_type(4))) unsigned short ushort4v;
typedef __attribute__((ext_vector_type(4))) unsigned int uint4v;

__device__ __forceinline__ unsigned short f2bf(float f) {
  unsigned int u = __float_as_uint(f);
  u += 0x7fffu + ((u >> 16) & 1u);   // RNE (finite data)
  return (unsigned short)(u >> 16);
}

// pack two f32 -> bf16x2 with round-half-up: 2 adds + 1 v_perm (vs ~8 ops RNE)
__device__ __forceinline__ unsigned int pk2t(float a, float b) {
  return __builtin_amdgcn_perm(__float_as_uint(b) + 0x8000u,
                               __float_as_uint(a) + 0x8000u, 0x07060302u);
}

__device__ __forceinline__ f32x4 mfma_16x16x32(bf16x8 a, bf16x8 b, f32x4 c) {
  return __builtin_amdgcn_mfma_f32_16x16x32_bf16(a, b, c, 0, 0, 0);
}

// async global->LDS, 16B per lane; LDS dest must be wave-uniform base + lane*16
__device__ __forceinline__ void async_ld16(const unsigned short* g, unsigned short* l) {
  __builtin_amdgcn_global_load_lds(
      (const __attribute__((address_space(1))) void*)g,
      (__attribute__((address_space(3))) void*)l, 16, 0, 0);
}

// -------------------- cast fp32 -> bf16 for 3 inputs + 4 weights --------------------
// Reverted to the r5 version: r8's in-proj fused cast spilled (VGPR-held staging) and
// ran 148us. Separate HBM-bound cast (~27us) + bf16 global_load_lds proj is best.
__global__ __launch_bounds__(256) void cast_all(
    const float* __restrict__ xq, const float* __restrict__ xk, const float* __restrict__ xv,
    const float* __restrict__ wq, const float* __restrict__ wk,
    const float* __restrict__ wv, const float* __restrict__ wo,
    unsigned short* __restrict__ ws) {
  int blk = blockIdx.x;
  const float* src; size_t dstoff; int rel;
  if (blk < 4096)       { src = xq; dstoff = 0;        rel = blk; }
  else if (blk < 8192)  { src = xk; dstoff = 8388608;  rel = blk - 4096; }
  else if (blk < 12288) { src = xv; dstoff = 16777216; rel = blk - 8192; }
  else if (blk < 12800) { src = wq; dstoff = 25165824; rel = blk - 12288; }
  else if (blk < 13312) { src = wk; dstoff = 26214400; rel = blk - 12800; }
  else if (blk < 13824) { src = wv; dstoff = 27262976; rel = blk - 13312; }
  else                  { src = wo; dstoff = 28311552; rel = blk - 13824; }
  size_t base = (size_t)rel * 2048 + (size_t)threadIdx.x * 8;
  float4 a = *(const float4*)(src + base);
  float4 b = *(const float4*)(src + base + 4);
  ushort4v o0, o1;
  o0.x = f2bf(a.x); o0.y = f2bf(a.y); o0.z = f2bf(a.z); o0.w = f2bf(a.w);
  o1.x = f2bf(b.x); o1.y = f2bf(b.y); o1.z = f2bf(b.z); o1.w = f2bf(b.w);
  *(ushort4v*)(ws + dstoff + base) = o0;
  *(ushort4v*)(ws + dstoff + base + 4) = o1;
}

// -------------------- fused Q/K/V projection --------------------
// r5 version verbatim (session best: 69.5-72us): 128x128, BK=64, counted-vmcnt dbuf
// schedule, T2 XOR-swizzle (conflicts 0), XCD-local n-major id map (FETCH 49MB).
// 1536 blocks, flat id: [0,512) Q, [512,1024) K, [1024,1536) V^T.
__global__ __launch_bounds__(256, 2) void fused_proj(
    const unsigned short* __restrict__ xq, const unsigned short* __restrict__ xk,
    const unsigned short* __restrict__ xv, const unsigned short* __restrict__ wq,
    const unsigned short* __restrict__ wk, const unsigned short* __restrict__ wv,
    const float* __restrict__ bq, const float* __restrict__ bk, const float* __restrict__ bv,
    unsigned short* __restrict__ Qb, unsigned short* __restrict__ Kb,
    unsigned short* __restrict__ Vtb) {
  const int id = blockIdx.x;
  const int tid = threadIdx.x;
  const int wave = tid >> 6, lane = tid & 63;
  const int quad = lane >> 4, l16 = lane & 15;
  const int wr = wave >> 1, wc = wave & 1;

  const unsigned short *A, *W;
  const float* bias;
  int mode, m0, n0;
  size_t zoff = 0;
  if (id < 512) {
    mode = 0; A = xq; W = wq; bias = bq;
    m0 = (id & 63) * 128; n0 = (id >> 6) * 128;          // n-major (XCD-local A)
  } else if (id < 1024) {
    int t = id - 512;
    mode = 1; A = xk; W = wk; bias = bk;
    m0 = (t & 63) * 128; n0 = (t >> 6) * 128;            // n-major
  } else {
    int t = id - 1024;
    int z = t >> 6;
    mode = 2; A = wv; W = xv + (size_t)z * 1048576; bias = bv;
    m0 = ((t >> 3) & 7) * 128; n0 = (t & 7) * 128;       // already XCD-local
    zoff = (size_t)z * 1048576;
  }

  __shared__ __align__(16) unsigned short As[2][128 * 64];
  __shared__ __align__(16) unsigned short Bs[2][128 * 64];

  const unsigned short* Wb = W + (size_t)n0 * 1024;

  f32x4 acc[4][4];
#pragma unroll
  for (int i = 0; i < 4; ++i)
#pragma unroll
    for (int j = 0; j < 4; ++j) acc[i][j] = (f32x4){0.f, 0.f, 0.f, 0.f};

  const int row_s = tid >> 3, c_s = tid & 7;
  const int swl = l16 & 7;           // read-side swizzle key (row&7 == l16&7)

  // stage tile kt into buffer sel: 8 async_ld16 per wave (vmcnt += 8)
  auto stage = [&](int sel, int kt) {
    const unsigned short* Akt = A + (size_t)m0 * 1024 + kt * 64;
    const unsigned short* Wkt = Wb + kt * 64;
#pragma unroll
    for (int i = 0; i < 4; ++i) {
      int g = i * 256 + tid;
      int row = row_s + i * 32;
      int gc = c_s ^ (row & 7);      // pre-swizzled global source chunk
      async_ld16(Akt + (size_t)row * 1024 + gc * 8, &As[sel][g * 8]);
      async_ld16(Wkt + (size_t)row * 1024 + gc * 8, &Bs[sel][g * 8]);
    }
  };

  stage(0, 0);                                   //  8 in flight
  stage(1, 1);                                   // 16 in flight
  asm volatile("s_waitcnt vmcnt(8)" ::: "memory");   // my buf0 loads landed
  __builtin_amdgcn_s_barrier();                  // everyone's buf0 landed -> ready

  for (int kt = 0; kt < 16; ++kt) {
    const int cur = kt & 1;
    // invariant: buf[cur] ready; buf[cur^1] loads (tile kt+1) in flight
#pragma unroll
    for (int ks = 0; ks < 2; ++ks) {
      bf16x8 af[4], bfv[4];
      const int sc = (ks * 4 + quad) ^ swl;      // swizzled LDS chunk slot
#pragma unroll
      for (int i = 0; i < 4; ++i)
        af[i] = *(const bf16x8*)(&As[cur][((wr * 64 + i * 16 + l16) * 8 + sc) * 8]);
#pragma unroll
      for (int j = 0; j < 4; ++j)
        bfv[j] = *(const bf16x8*)(&Bs[cur][((wc * 64 + j * 16 + l16) * 8 + sc) * 8]);
      __builtin_amdgcn_s_setprio(1);
#pragma unroll
      for (int i = 0; i < 4; ++i)
#pragma unroll
        for (int j = 0; j < 4; ++j) acc[i][j] = mfma_16x16x32(af[i], bfv[j], acc[i][j]);
      __builtin_amdgcn_s_setprio(0);
    }
    __builtin_amdgcn_s_barrier();                // B1: all waves done READING buf[cur]
    int ktc = kt + 2 > 15 ? 15 : kt + 2;         // clamp: tail re-stages tile 15 (never read)
    stage(cur, ktc);                             // overwrite buf[cur]; 8+8 in flight
    asm volatile("s_waitcnt vmcnt(8)" ::: "memory"); // tile kt+1 landed (new 8 in flight)
    __builtin_amdgcn_s_barrier();                // B2: buf[cur^1] collectively ready
  }

  if (mode == 2) {
    size_t base = zoff;
    const int nxor = ((((l16 >> 2) + 1) & 2) ? 12 : 0);
#pragma unroll
    for (int i = 0; i < 4; ++i)
#pragma unroll
      for (int r = 0; r < 4; ++r) {
        int m = m0 + wr * 64 + i * 16 + quad * 4 + r;
        float bm = bias[m];
#pragma unroll
        for (int j = 0; j < 4; ++j) {
          int n = (n0 + wc * 64 + j * 16 + l16) ^ nxor;
          Vtb[base + (size_t)m * 1024 + n] = f2bf(acc[i][j][r] + bm);
        }
      }
  } else {
    unsigned short* Out = (mode == 0) ? Qb : Kb;
    const float scale = (mode == 0) ? L2E8 : 1.0f;
#pragma unroll
    for (int j = 0; j < 4; ++j) {
      int n = n0 + wc * 64 + j * 16 + l16;
      float bn = bias[n];
      int h = n >> 6, d = n & 63;
#pragma unroll
      for (int i = 0; i < 4; ++i)
#pragma unroll
        for (int r = 0; r < 4; ++r) {
          int m = m0 + wr * 64 + i * 16 + quad * 4 + r;
          int b = m >> 10, t = m & 1023;
          float v = (acc[i][j][r] + bn) * scale;
          Out[((size_t)((b << 4) + h) * 1024 + t) * 64 + d] = f2bf(v);
        }
    }
  }
}

// -------------------- final GEMM: out = O @ Wo^T + bo (fp32 out) --------------------
// Round-9: upgraded to the proj-proven 128x128 body (4x4 acc, 8-load counted-vmcnt
// schedule, T2 swizzle) -- 2x MFMA density and 33% less staging redundancy vs the
// old 64x128 tile. Only the A addressing ((B,H,T,D): m=b*1024+t, k-tile kt = head h,
// row stride 64) and the fp32 epilogue differ from fused_proj.
// Grid (64,8): A-panel siblings (same bx, by varying) at flat-id stride 64 == 0 mod 8
// -> same XCD (A fetched once per XCD-set). LDS 64KB -> 2 blocks/CU.
__global__ __launch_bounds__(256, 2) void gemm_out(
    const unsigned short* __restrict__ A, const unsigned short* __restrict__ Wm,
    const float* __restrict__ bias, float* __restrict__ Cout) {
  const int tid = threadIdx.x;
  const int wave = tid >> 6, lane = tid & 63;
  const int quad = lane >> 4, l16 = lane & 15;
  const int wr = wave >> 1, wc = wave & 1;   // wave tile: 64m x 64n
  const int m0 = blockIdx.x * 128;
  const int n0 = blockIdx.y * 128;

  __shared__ __align__(16) unsigned short As[2][128 * 64];
  __shared__ __align__(16) unsigned short Bs[2][128 * 64];

  const unsigned short* Wb = Wm + (size_t)n0 * 1024;

  f32x4 acc[4][4];
#pragma unroll
  for (int i = 0; i < 4; ++i)
#pragma unroll
    for (int j = 0; j < 4; ++j) acc[i][j] = (f32x4){0.f, 0.f, 0.f, 0.f};

  const int row_s = tid >> 3, c_s = tid & 7;
  const int swl = l16 & 7;

  // stage K-tile kt (= head kt): A 128x64 (row stride 64) + B 128x64; 8 loads/thread
  auto stage = [&](int sel, int kt) {
    const unsigned short* Akt = A + (size_t)(m0 >> 10) * 1048576 +
                                (size_t)kt * 65536 + (size_t)(m0 & 1023) * 64;
    const unsigned short* Wkt = Wb + kt * 64;
#pragma unroll
    for (int i = 0; i < 4; ++i) {
      int g = i * 256 + tid;
      int row = row_s + i * 32;
      int gc = c_s ^ (row & 7);
      async_ld16(Akt + (size_t)row * 64 + gc * 8, &As[sel][g * 8]);
      async_ld16(Wkt + (size_t)row * 1024 + gc * 8, &Bs[sel][g * 8]);
    }
  };

  stage(0, 0);                                   //  8 in flight
  stage(1, 1);                                   // 16 in flight
  asm volatile("s_waitcnt vmcnt(8)" ::: "memory");
  __builtin_amdgcn_s_barrier();

  for (int kt = 0; kt < 16; ++kt) {
    const int cur = kt & 1;
#pragma unroll
    for (int ks = 0; ks < 2; ++ks) {
      bf16x8 af[4], bfv[4];
      const int sc = (ks * 4 + quad) ^ swl;
#pragma unroll
      for (int i = 0; i < 4; ++i)
        af[i] = *(const bf16x8*)(&As[cur][((wr * 64 + i * 16 + l16) * 8 + sc) * 8]);
#pragma unroll
      for (int j = 0; j < 4; ++j)
        bfv[j] = *(const bf16x8*)(&Bs[cur][((wc * 64 + j * 16 + l16) * 8 + sc) * 8]);
      __builtin_amdgcn_s_setprio(1);
#pragma unroll
      for (int i = 0; i < 4; ++i)
#pragma unroll
        for (int j = 0; j < 4; ++j) acc[i][j] = mfma_16x16x32(af[i], bfv[j], acc[i][j]);
      __builtin_amdgcn_s_setprio(0);
    }
    __builtin_amdgcn_s_barrier();                // B1: done reading buf[cur]
    int ktc = kt + 2 > 15 ? 15 : kt + 2;
    stage(cur, ktc);
    asm volatile("s_waitcnt vmcnt(8)" ::: "memory");
    __builtin_amdgcn_s_barrier();                // B2: buf[cur^1] ready
  }

#pragma unroll
  for (int j = 0; j < 4; ++j) {
    int n = n0 + wc * 64 + j * 16 + l16;
    float bn = bias[n];
#pragma unroll
    for (int i = 0; i < 4; ++i)
#pragma unroll
      for (int r = 0; r < 4; ++r) {
        int m = m0 + wr * 64 + i * 16 + quad * 4 + r;
        Cout[(size_t)m * 1024 + n] = acc[i][j][r] + bn;
      }
  }
}

// -------------------- attention: S^T form + LDS-staged K/V tiles --------------------
// r5 version (16 q-rows/wave, grid (128,16); best measured net). setprio (T5).
__global__ __launch_bounds__(256) void attn(
    const unsigned short* __restrict__ Q,   // (B,H,T,D), pre-scaled by log2e/8
    const unsigned short* __restrict__ K,   // (B,H,T,D)
    const unsigned short* __restrict__ Vt,  // (B,H,D,T), T pi-permuted per 32-block
    unsigned short* __restrict__ O) {       // (B,H,T,D)
  const int bh = blockIdx.x;
  const int tid = threadIdx.x;
  const int wave = tid >> 6, lane = tid & 63;
  const int quad = lane >> 4, l16 = lane & 15;
  const int q0 = blockIdx.y * 64 + wave * 16;
  const size_t bhTD = (size_t)bh * (TT * DD);
  const unsigned short* Qb = Q + bhTD;
  const unsigned short* Kb = K + bhTD;
  const unsigned short* Vb = Vt + bhTD;

  __shared__ __align__(16) unsigned short Ks[64 * 64];
  __shared__ __align__(16) unsigned short Vs[64 * 64];

  bf16x8 q_lo = *(const bf16x8*)(Qb + (size_t)(q0 + l16) * 64 + quad * 8);
  bf16x8 q_hi = *(const bf16x8*)(Qb + (size_t)(q0 + l16) * 64 + 32 + quad * 8);

  uint4v ou; ou.x = ou.y = ou.z = ou.w = 0x3F803F80u;   // bf16 1.0 x8
  const bf16x8 ones = __builtin_bit_cast(bf16x8, ou);

  f32x4 o_acc[4];
#pragma unroll
  for (int dd = 0; dd < 4; ++dd) o_acc[dd] = (f32x4){0.f, 0.f, 0.f, 0.f};
  f32x4 acc5 = (f32x4){0.f, 0.f, 0.f, 0.f};             // per-row sum of P-hat
  const bool lo_half = (quad < 2);

  const int srow = tid >> 3;
  const int schunk = tid & 7;

  for (int it = 0; it < 16; ++it) {
    const int kv0 = it * 64;
#pragma unroll
    for (int i = 0; i < 2; ++i) {
      int row = srow + i * 32;
      int gc = schunk ^ (row & 7);
      async_ld16(Kb + (size_t)(kv0 + row) * 64 + gc * 8, Ks + (row * 8 + schunk) * 8);
      async_ld16(Vb + (size_t)row * 1024 + kv0 + gc * 8, Vs + (row * 8 + schunk) * 8);
    }
    __syncthreads();

    // ---- phase 1: all S-MFMAs for both 32-kv halves ----
    f32x4 f[4];
#pragma unroll
    for (int c = 0; c < 2; ++c) {
      const int r0 = c * 32 + l16;
      const int r1 = r0 + 16;
      const int sw = r0 & 7;
      bf16x8 k00 = *(const bf16x8*)(Ks + (r0 * 8 + (quad ^ sw)) * 8);
      bf16x8 k01 = *(const bf16x8*)(Ks + (r0 * 8 + ((quad + 4) ^ sw)) * 8);
      bf16x8 k10 = *(const bf16x8*)(Ks + (r1 * 8 + (quad ^ sw)) * 8);
      bf16x8 k11 = *(const bf16x8*)(Ks + (r1 * 8 + ((quad + 4) ^ sw)) * 8);
      f32x4 a = (f32x4){0.f, 0.f, 0.f, 0.f};
      f32x4 b = (f32x4){0.f, 0.f, 0.f, 0.f};
      __builtin_amdgcn_s_setprio(1);
      a = mfma_16x16x32(k00, q_lo, a);
      a = mfma_16x16x32(k01, q_hi, a);
      b = mfma_16x16x32(k10, q_lo, b);
      b = mfma_16x16x32(k11, q_hi, b);
      __builtin_amdgcn_s_setprio(0);
      f[2 * c] = a; f[2 * c + 1] = b;
    }

    // ---- phase 2: exp2, pack, A-frag build, denominator + PV MFMAs ----
#pragma unroll
    for (int c = 0; c < 2; ++c) {
      f32x4 f0 = f[2 * c], f1 = f[2 * c + 1];
      float p0 = __builtin_amdgcn_exp2f(f0[0]), p1 = __builtin_amdgcn_exp2f(f0[1]);
      float p2 = __builtin_amdgcn_exp2f(f0[2]), p3 = __builtin_amdgcn_exp2f(f0[3]);
      float p4 = __builtin_amdgcn_exp2f(f1[0]), p5 = __builtin_amdgcn_exp2f(f1[1]);
      float p6 = __builtin_amdgcn_exp2f(f1[2]), p7 = __builtin_amdgcn_exp2f(f1[3]);
      unsigned int u01 = pk2t(p0, p1), u23 = pk2t(p2, p3);
      unsigned int u45 = pk2t(p4, p5), u67 = pk2t(p6, p7);
      unsigned int pu01 = __shfl_xor(u01, 32), pu23 = __shfl_xor(u23, 32);
      unsigned int pu45 = __shfl_xor(u45, 32), pu67 = __shfl_xor(u67, 32);
      uint4v av;
      av.x = lo_half ? u01 : pu45;
      av.y = lo_half ? u23 : pu67;
      av.z = lo_half ? pu01 : u45;
      av.w = lo_half ? pu23 : u67;
      bf16x8 ap = __builtin_bit_cast(bf16x8, av);
      __builtin_amdgcn_s_setprio(1);
      acc5 = mfma_16x16x32(ap, ones, acc5);
#pragma unroll
      for (int dd = 0; dd < 4; ++dd) {
        int vr = dd * 16 + l16;
        bf16x8 bv = *(const bf16x8*)(Vs + (vr * 8 + ((c * 4 + quad) ^ (vr & 7))) * 8);
        o_acc[dd] = mfma_16x16x32(ap, bv, o_acc[dd]);
      }
      __builtin_amdgcn_s_setprio(0);
    }
    __syncthreads();
  }
#pragma unroll
  for (int r = 0; r < 4; ++r) {
    float invr = 1.f / acc5[r];    // acc5[r] = sum_k P[q=quad*4+r][k], same at every lane
    int trow = q0 + quad * 4 + r;
#pragma unroll
    for (int dd = 0; dd < 4; ++dd)
      O[bhTD + (size_t)trow * 64 + dd * 16 + l16] = f2bf(o_acc[dd][r] * invr);
  }
}

// -------------------- launch --------------------
extern "C" void kernel_launch(void* const* d_in, const int* in_sizes, int n_in,
                              void* d_out, int out_size, void* d_ws, size_t ws_size,
                              hipStream_t stream) {
  const float* xq = (const float*)d_in[0];
  const float* xk = (const float*)d_in[1];
  const float* xv = (const float*)d_in[2];
  const float* Wq = (const float*)d_in[3];
  const float* bq = (const float*)d_in[4];
  const float* Wk = (const float*)d_in[5];
  const float* bk = (const float*)d_in[6];
  const float* Wv = (const float*)d_in[7];
  const float* bv = (const float*)d_in[8];
  const float* Wo = (const float*)d_in[9];
  const float* bo = (const float*)d_in[10];

  unsigned short* ws = (unsigned short*)d_ws;
  unsigned short* xq_b = ws;                 // 8388608
  unsigned short* xk_b = ws + 8388608;
  unsigned short* xv_b = ws + 16777216;
  unsigned short* wq_b = ws + 25165824;      // 1048576 each
  unsigned short* wk_b = ws + 26214400;
  unsigned short* wv_b = ws + 27262976;
  unsigned short* wo_b = ws + 28311552;
  unsigned short* Qbuf = ws + 29360128;      // (B,H,T,D)
  unsigned short* Kbuf = ws + 37748736;      // (B,H,T,D)
  unsigned short* Vtb  = ws + 46137344;      // (B,H,D,T) pi-permuted
  unsigned short* Obuf = ws + 54525952;      // (B,H,T,D)

  cast_all<<<14336, 256, 0, stream>>>(xq, xk, xv, Wq, Wk, Wv, Wo, ws);

  fused_proj<<<1536, 256, 0, stream>>>(xq_b, xk_b, xv_b, wq_b, wk_b, wv_b,
                                       bq, bk, bv, Qbuf, Kbuf, Vtb);
  attn<<<dim3(128, 16), 256, 0, stream>>>(Qbuf, Kbuf, Vtb, Obuf);
  gemm_out<<<dim3(64, 8), 256, 0, stream>>>(Obuf, wo_b, bo, (float*)d_out);
}